// Round 2
// baseline (28.191 us; speedup 1.0000x reference)
//
#include <hip/hip_runtime.h>

// out[b,o] = sum_{i,n} (Ps*tanh(k*(x + Ec*bm)) + bias) * coef
// bm = 1 - 0.4*(1 - sigmoid(10*(x_b - x_{b-1}))) * sigmoid(10*(-x - Ec))
// (switch_up cancels algebraically: target = 1 - 2*switch_lo)
//
// tanh(a) = 1 - 2/(exp(2a)+1)  ->  out = base[o] - 2 * sum pc*r
//   base[o] = sum (Ps + bias)*coef   (batch-independent, block-reduced once)
//   pc = Ps*coef, r = rcp(exp2(k2*inner)+1), k2 = 2*log2(e)*k
//
// R2: BT 32->16 + i-split-2 per thread. LDS 49KB->33KB => 4 blocks/CU
// (was 3), grid 2048 = 8/CU = two balanced occupancy rounds (was 4/CU on
// 3-resident => tail round at 1/CU).

#define GATE_C 14.426950408889634f   // 10*log2(e)
#define TANH_C 2.8853900817779268f   // 2*log2(e)

constexpr int B = 512, I = 128, O = 64, NB = 8, BT = 16;

__global__ __launch_bounds__(256, 4) void fe_main(
    const float* __restrict__ x, const float* __restrict__ k,
    const float* __restrict__ Ec, const float* __restrict__ Ps,
    const float* __restrict__ bias, const float* __restrict__ coef,
    float* __restrict__ out)
{
  __shared__ float4 p_lds[I * NB];        // {Ec, Ec*GATE_C, k*TANH_C, Ps*coef}, [i][n]
  __shared__ float2 xc_lds[BT][I + 1];    // {x, c}; +1 pad keeps reads <=2-way
  __shared__ float red[4];

  const int tid = threadIdx.x;
  const int o  = blockIdx.y;
  const int b0 = blockIdx.x * BT;

  // ---- stage packed params for this o, accumulate base[o] partial ----
  float pbase = 0.f;
  for (int e = tid; e < I * NB; e += 256) {
    const int i = e >> 3, n = e & 7;
    const int g = (i * O + o) * NB + n;
    const float ec = Ec[g], kk = k[g], ps = Ps[g], cf = coef[g], bs = bias[g];
    const float pc = ps * cf;
    p_lds[e] = make_float4(ec, ec * GATE_C, kk * TANH_C, pc);
    pbase += fmaf(bs, cf, pc);
  }

  // ---- stage {x, c} for this batch tile (coalesced global reads) ----
  for (int e = tid; e < BT * I; e += 256) {
    const int bl = e >> 7, i = e & 127;
    const int bg = b0 + bl;
    const float xv = x[bg * I + i];
    const float pv = (bg == 0) ? 0.f : x[(bg - 1) * I + i];
    // c = -0.4 * (1 - sigmoid(10*dx)) = -0.4 * sigmoid(-10*dx)
    const float c = -0.4f * __builtin_amdgcn_rcpf(
        1.f + __builtin_amdgcn_exp2f(GATE_C * (xv - pv)));
    xc_lds[bl][i] = make_float2(xv, c);
  }

  // base partial: full-wave butterfly, one partial per wave
  #pragma unroll
  for (int m = 1; m < 64; m <<= 1) pbase += __shfl_xor(pbase, m);
  if ((tid & 63) == 0) red[tid >> 6] = pbase;
  __syncthreads();

  // ---- main loop: thread = (bl, ih, n); reduce over 64 i's ----
  const int bl = tid >> 4, ih = (tid >> 3) & 1, n = tid & 7;
  const float4* __restrict__ prow = p_lds + (ih * 64) * 8 + n;
  const float2* __restrict__ xrow = &xc_lds[bl][ih * 64];

  float acc = 0.f;
  #pragma unroll 8
  for (int it = 0; it < 64; ++it) {
    const float2 xc = xrow[it];         // broadcast across n-lanes
    const float4 p  = prow[it * 8];     // broadcast across bl-lanes
    // crossed_neg = rcp(1 + exp2(GATE_C*x + GATE_C*Ec))
    const float sg = __builtin_amdgcn_rcpf(
        1.f + __builtin_amdgcn_exp2f(fmaf(xc.x, GATE_C, p.y)));
    const float bm    = fmaf(xc.y, sg, 1.f);        // 1 + c*sg
    const float inner = fmaf(p.x, bm, xc.x);        // x + Ec*bm
    const float r = __builtin_amdgcn_rcpf(
        1.f + __builtin_amdgcn_exp2f(p.z * inner)); // rcp(exp(2a)+1)
    acc = fmaf(p.w, r, acc);                        // sum pc*r
  }

  // reduce over n (dist 1,2,4) then ih (dist 8) — all within wave
  acc += __shfl_xor(acc, 1);
  acc += __shfl_xor(acc, 2);
  acc += __shfl_xor(acc, 4);
  acc += __shfl_xor(acc, 8);

  if ((tid & 15) == 0) {
    const float base = red[0] + red[1] + red[2] + red[3];
    out[(b0 + bl) * O + o] = fmaf(-2.f, acc, base);
  }
}

extern "C" void kernel_launch(void* const* d_in, const int* in_sizes, int n_in,
                              void* d_out, int out_size, void* d_ws, size_t ws_size,
                              hipStream_t stream) {
  const float* x    = (const float*)d_in[0];
  const float* k    = (const float*)d_in[1];
  const float* Ec   = (const float*)d_in[2];
  const float* Ps   = (const float*)d_in[3];
  const float* bias = (const float*)d_in[4];
  const float* coef = (const float*)d_in[5];
  float* out = (float*)d_out;

  dim3 grid(B / BT, O);   // 32 batch tiles x 64 output channels
  fe_main<<<grid, 256, 0, stream>>>(x, k, Ec, Ps, bias, coef, out);
}